// Round 1
// baseline (1001.128 us; speedup 1.0000x reference)
//
#include <hip/hip_runtime.h>
#include <math.h>

#define HWp 16384
#define CH 64
#define KC 8

// ws float offsets
#define OFF_WQ1 0
#define OFF_WK1 4224
#define OFF_WV1 8448
#define OFF_WQ2 12544
#define OFF_WK2 20864
#define OFF_WV2 29184
#define OFF_WO  37376
#define OFF_BQ1 41472
#define OFF_BK1 41536
#define OFF_BV1 41600
#define OFF_BQ2 41664
#define OFF_BK2 41728
#define OFF_BV2 41792
#define OFF_Z   41856   // zbuf: B*HW*64 floats

#define FMA16(ACC, A, W) \
  ACC[0][0] += A.x * W.x; ACC[0][1] += A.x * W.y; ACC[0][2] += A.x * W.z; ACC[0][3] += A.x * W.w; \
  ACC[1][0] += A.y * W.x; ACC[1][1] += A.y * W.y; ACC[1][2] += A.y * W.z; ACC[1][3] += A.y * W.w; \
  ACC[2][0] += A.z * W.x; ACC[2][1] += A.z * W.y; ACC[2][2] += A.z * W.z; ACC[2][3] += A.z * W.w; \
  ACC[3][0] += A.w * W.x; ACC[3][1] += A.w * W.y; ACC[3][2] += A.w * W.z; ACC[3][3] += A.w * W.w;

// Fold MHA in-projection into the q/k/v linears: WT[c][e] = sum_f ip[(off+e)][f]*lw[f][c]
__global__ void setup_weights(const float* __restrict__ q1w, const float* __restrict__ q1b,
                              const float* __restrict__ k1w, const float* __restrict__ k1b,
                              const float* __restrict__ v1w, const float* __restrict__ v1b,
                              const float* __restrict__ q2w, const float* __restrict__ q2b,
                              const float* __restrict__ k2w, const float* __restrict__ k2b,
                              const float* __restrict__ v2w, const float* __restrict__ v2b,
                              const float* __restrict__ ipw, const float* __restrict__ ipb,
                              const float* __restrict__ ow, float* __restrict__ ws) {
  int id = blockIdx.y;
  int idx = blockIdx.x * 256 + threadIdx.x;
  if (id == 6) {  // transpose out_w: WT_O[d][e] = out_w[e][d]
    if (idx < 4096) { int d = idx >> 6, e = idx & 63; ws[OFF_WO + d * 64 + e] = ow[e * 64 + d]; }
    return;
  }
  const float* lw; const float* lb; int K, off, wo, bo;
  switch (id) {
    case 0:  lw = q1w; lb = q1b; K = 66;  off = 0;   wo = OFF_WQ1; bo = OFF_BQ1; break;
    case 1:  lw = k1w; lb = k1b; K = 66;  off = 64;  wo = OFF_WK1; bo = OFF_BK1; break;
    case 2:  lw = v1w; lb = v1b; K = 64;  off = 128; wo = OFF_WV1; bo = OFF_BV1; break;
    case 3:  lw = q2w; lb = q2b; K = 130; off = 0;   wo = OFF_WQ2; bo = OFF_BQ2; break;
    case 4:  lw = k2w; lb = k2b; K = 130; off = 64;  wo = OFF_WK2; bo = OFF_BK2; break;
    default: lw = v2w; lb = v2b; K = 128; off = 128; wo = OFF_WV2; bo = OFF_BV2; break;
  }
  if (idx < K * 64) {
    int c = idx >> 6, e = idx & 63;
    float s = 0.f;
    for (int f = 0; f < 64; ++f) s += ipw[(off + e) * 64 + f] * lw[f * K + c];
    ws[wo + c * 64 + e] = s;
  } else if (idx < K * 64 + 64) {
    int e = idx - K * 64;
    float s = ipb[off + e];
    for (int f = 0; f < 64; ++f) s += ipw[(off + e) * 64 + f] * lb[f];
    ws[bo + e] = s;
  }
}

// ---------------- Stage 1: 8 pixels / 64 key rows per block ----------------
__global__ __launch_bounds__(256) void stage1(const float* __restrict__ HFs,
                                              const float* __restrict__ HFc,
                                              const float* __restrict__ Zc,
                                              float* __restrict__ ws,
                                              const float* __restrict__ outb) {
  const int t = threadIdx.x;
  const int tile = blockIdx.x;
  const int b = tile >> 11;              // 2048 tiles per batch
  const int p0 = (tile & 2047) << 3;     // first query pixel in batch
  const int m0 = p0 << 3;                // first flat candidate row (mult of 64)
  const int k0 = m0 >> 14;               // candidate slab
  const int poff = m0 & (HWp - 1);       // pixel offset of key rows (no wrap in tile)

  __shared__ __align__(16) float XG[64 * 64];  // X^T[c][row]
  __shared__ __align__(16) float XQ[64 * 8];   // Qpix^T[c][pl]
  __shared__ __align__(16) float KH[64 * 64];  // [row][e]
  __shared__ __align__(16) float VH[64 * 64];
  __shared__ __align__(16) float QH[8 * 64];
  __shared__ __align__(16) float AO[8 * 64];

  const int ml = t & 63, c0 = t >> 6;
  const size_t base_k = ((size_t)(b * KC + k0) * CH) * HWp + poff;

  // stage Kc (coalesced: ml contiguous) and Qpix
  for (int i = 0; i < 16; ++i) {
    int c = c0 * 16 + i;
    XG[c * 64 + ml] = HFc[base_k + (size_t)c * HWp + ml];
  }
  {
    int pl = t & 7, cq = t >> 3;  // cq 0..31
    const float* gq = HFs + (size_t)b * CH * HWp + p0;
    XQ[cq * 8 + pl]        = gq[(size_t)cq * HWp + pl];
    XQ[(cq + 32) * 8 + pl] = gq[(size_t)(cq + 32) * HWp + pl];
  }
  __syncthreads();

  const int rg = t >> 4, cg = t & 15;
  float acc[4][4];

  // ---- KH = [Kc, coords] @ Wk1c^T + bk1c  (coords+bias folded into init)
  {
    const float* Wk = ws + OFF_WK1;
    const float* bk = ws + OFF_BK1;
    for (int r = 0; r < 4; ++r) {
      int pp = poff + rg * 4 + r;
      float ig = (float)(pp >> 7) * (1.f / 127.f);
      float jg = (float)(pp & 127) * (1.f / 127.f);
      for (int c = 0; c < 4; ++c)
        acc[r][c] = bk[cg * 4 + c] + ig * Wk[64 * 64 + cg * 4 + c] + jg * Wk[65 * 64 + cg * 4 + c];
    }
#pragma unroll 4
    for (int kk = 0; kk < 64; ++kk) {
      const float4 a = *(const float4*)&XG[kk * 64 + rg * 4];
      const float4 w = *(const float4*)&Wk[kk * 64 + cg * 4];
      FMA16(acc, a, w)
    }
    for (int r = 0; r < 4; ++r)
      *(float4*)&KH[(rg * 4 + r) * 64 + cg * 4] =
          make_float4(acc[r][0], acc[r][1], acc[r][2], acc[r][3]);
  }
  // ---- QH (only 128 threads; M=8)
  if (t < 128) {
    int row = t >> 4, cq = t & 15;
    const float* Wq = ws + OFF_WQ1;
    const float* bq = ws + OFF_BQ1;
    int p = p0 + row;
    float ig = (float)(p >> 7) * (1.f / 127.f);
    float jg = (float)(p & 127) * (1.f / 127.f);
    float a0[4];
    for (int c = 0; c < 4; ++c)
      a0[c] = bq[cq * 4 + c] + ig * Wq[64 * 64 + cq * 4 + c] + jg * Wq[65 * 64 + cq * 4 + c];
#pragma unroll 4
    for (int kk = 0; kk < 64; ++kk) {
      float a = XQ[kk * 8 + row];
      const float4 w = *(const float4*)&Wq[kk * 64 + cq * 4];
      a0[0] += a * w.x; a0[1] += a * w.y; a0[2] += a * w.z; a0[3] += a * w.w;
    }
    *(float4*)&QH[row * 64 + cq * 4] = make_float4(a0[0], a0[1], a0[2], a0[3]);
  }
  __syncthreads();

  // restage XG <- Zc
  for (int i = 0; i < 16; ++i) {
    int c = c0 * 16 + i;
    XG[c * 64 + ml] = Zc[base_k + (size_t)c * HWp + ml];
  }
  __syncthreads();

  // ---- VH = Zc @ Wv1c^T + bv1c
  {
    const float* Wv = ws + OFF_WV1;
    const float* bv = ws + OFF_BV1;
    for (int r = 0; r < 4; ++r)
      for (int c = 0; c < 4; ++c) acc[r][c] = bv[cg * 4 + c];
#pragma unroll 4
    for (int kk = 0; kk < 64; ++kk) {
      const float4 a = *(const float4*)&XG[kk * 64 + rg * 4];
      const float4 w = *(const float4*)&Wv[kk * 64 + cg * 4];
      FMA16(acc, a, w)
    }
    for (int r = 0; r < 4; ++r)
      *(float4*)&VH[(rg * 4 + r) * 64 + cg * 4] =
          make_float4(acc[r][0], acc[r][1], acc[r][2], acc[r][3]);
  }
  __syncthreads();

  // ---- attention: thread per (pixel, head)
  if (t < 32) {
    int pl = t >> 2, h = t & 3;
    float q[16];
    for (int d = 0; d < 16; ++d) q[d] = QH[pl * 64 + h * 16 + d];
    float s[8], mx = -1e30f;
    for (int k = 0; k < 8; ++k) {
      float sc = 0.f;
      for (int d = 0; d < 16; ++d) sc += q[d] * KH[(pl * 8 + k) * 64 + h * 16 + d];
      s[k] = sc * 0.25f;
      mx = fmaxf(mx, s[k]);
    }
    float sum = 0.f;
    for (int k = 0; k < 8; ++k) { s[k] = expf(s[k] - mx); sum += s[k]; }
    float inv = 1.f / sum;
    for (int d = 0; d < 16; ++d) {
      float o = 0.f;
      for (int k = 0; k < 8; ++k) o += s[k] * VH[(pl * 8 + k) * 64 + h * 16 + d];
      AO[pl * 64 + h * 16 + d] = o * inv;
    }
  }
  __syncthreads();

  // ---- out projection -> zbuf
  if (t < 128) {
    int row = t >> 4, cq = t & 15;
    const float* Wo = ws + OFF_WO;
    float a0[4];
    for (int c = 0; c < 4; ++c) a0[c] = outb[cq * 4 + c];
#pragma unroll 4
    for (int kk = 0; kk < 64; ++kk) {
      float a = AO[row * 64 + kk];
      const float4 w = *(const float4*)&Wo[kk * 64 + cq * 4];
      a0[0] += a * w.x; a0[1] += a * w.y; a0[2] += a * w.z; a0[3] += a * w.w;
    }
    float* zb = ws + OFF_Z + ((size_t)(b * HWp + p0 + row)) * 64;
    *(float4*)&zb[cq * 4] = make_float4(a0[0], a0[1], a0[2], a0[3]);
  }
}

// ---------------- Stage 2 ----------------
__global__ __launch_bounds__(256) void stage2(const float* __restrict__ HFs,
                                              const float* __restrict__ HFc,
                                              const float* __restrict__ Zc,
                                              float* __restrict__ ws,
                                              const float* __restrict__ outb,
                                              float* __restrict__ out) {
  const int t = threadIdx.x;
  const int tile = blockIdx.x;
  const int b = tile >> 11;
  const int p0 = (tile & 2047) << 3;
  const int m0 = p0 << 3;
  const int k0 = m0 >> 14;
  const int poff = m0 & (HWp - 1);

  __shared__ __align__(16) float XG[64 * 64];
  __shared__ __align__(16) float XQ2[128 * 8];
  __shared__ __align__(16) float KH[64 * 64];
  __shared__ __align__(16) float VH[64 * 64];
  __shared__ __align__(16) float QH[8 * 64];
  __shared__ __align__(16) float AO[8 * 64];

  const int ml = t & 63, c0 = t >> 6;
  const size_t base_k = ((size_t)(b * KC + k0) * CH) * HWp + poff;

  // phase 1: stage XG <- Kc, XQ2 <- [Qpix | z(query)]
  for (int i = 0; i < 16; ++i) {
    int c = c0 * 16 + i;
    XG[c * 64 + ml] = HFc[base_k + (size_t)c * HWp + ml];
  }
  {
    int pl = t & 7, cq = t >> 3;  // 0..31
    const float* gq = HFs + (size_t)b * CH * HWp + p0;
    XQ2[cq * 8 + pl]        = gq[(size_t)cq * HWp + pl];
    XQ2[(cq + 32) * 8 + pl] = gq[(size_t)(cq + 32) * HWp + pl];
    const float* zq = ws + OFF_Z + ((size_t)(b * HWp + p0)) * 64;
    XQ2[(64 + cq) * 8 + pl] = zq[(size_t)pl * 64 + cq];
    XQ2[(96 + cq) * 8 + pl] = zq[(size_t)pl * 64 + 32 + cq];
  }
  __syncthreads();

  const int rg = t >> 4, cg = t & 15;
  float ak[4][4], av[4][4];

  // phase 2: ak = bias + coords + Kc @ Wk2c[0:64]
  {
    const float* Wk = ws + OFF_WK2;
    const float* bk = ws + OFF_BK2;
    for (int r = 0; r < 4; ++r) {
      int pp = poff + rg * 4 + r;  // key pixel
      float ig = (float)(pp >> 7) * (1.f / 127.f);
      float jg = (float)(pp & 127) * (1.f / 127.f);
      for (int c = 0; c < 4; ++c)
        ak[r][c] = bk[cg * 4 + c] + ig * Wk[128 * 64 + cg * 4 + c] + jg * Wk[129 * 64 + cg * 4 + c];
    }
#pragma unroll 4
    for (int kk = 0; kk < 64; ++kk) {
      const float4 a = *(const float4*)&XG[kk * 64 + rg * 4];
      const float4 w = *(const float4*)&Wk[kk * 64 + cg * 4];
      FMA16(ak, a, w)
    }
  }
  __syncthreads();

  // phase 3: restage XG <- z at key pixels (z[b, (m0+ml)%HW])
  {
    const float* zk = ws + OFF_Z + ((size_t)(b * HWp + poff)) * 64;
    for (int i = 0; i < 16; ++i) {
      int c = c0 * 16 + i;
      XG[c * 64 + ml] = zk[(size_t)ml * 64 + c];
    }
  }
  __syncthreads();

  // phase 4: ak += z @ Wk2c[64:128]; av = bias + z @ Wv2c[64:128]; write KH; QH
  {
    const float* Wk = ws + OFF_WK2 + 64 * 64;
    const float* Wv = ws + OFF_WV2 + 64 * 64;
    const float* bv = ws + OFF_BV2;
    for (int r = 0; r < 4; ++r)
      for (int c = 0; c < 4; ++c) av[r][c] = bv[cg * 4 + c];
#pragma unroll 2
    for (int kk = 0; kk < 64; ++kk) {
      const float4 a  = *(const float4*)&XG[kk * 64 + rg * 4];
      const float4 wk = *(const float4*)&Wk[kk * 64 + cg * 4];
      const float4 wv = *(const float4*)&Wv[kk * 64 + cg * 4];
      FMA16(ak, a, wk)
      FMA16(av, a, wv)
    }
    for (int r = 0; r < 4; ++r)
      *(float4*)&KH[(rg * 4 + r) * 64 + cg * 4] = make_float4(ak[r][0], ak[r][1], ak[r][2], ak[r][3]);
  }
  if (t < 128) {  // QH: [Qpix,z,coords] @ Wq2c^T
    int row = t >> 4, cq = t & 15;
    const float* Wq = ws + OFF_WQ2;
    const float* bq = ws + OFF_BQ2;
    int p = p0 + row;
    float ig = (float)(p >> 7) * (1.f / 127.f);
    float jg = (float)(p & 127) * (1.f / 127.f);
    float a0[4];
    for (int c = 0; c < 4; ++c)
      a0[c] = bq[cq * 4 + c] + ig * Wq[128 * 64 + cq * 4 + c] + jg * Wq[129 * 64 + cq * 4 + c];
#pragma unroll 4
    for (int kk = 0; kk < 128; ++kk) {
      float a = XQ2[kk * 8 + row];
      const float4 w = *(const float4*)&Wq[kk * 64 + cq * 4];
      a0[0] += a * w.x; a0[1] += a * w.y; a0[2] += a * w.z; a0[3] += a * w.w;
    }
    *(float4*)&QH[row * 64 + cq * 4] = make_float4(a0[0], a0[1], a0[2], a0[3]);
  }
  __syncthreads();

  // phase 5: restage XG <- Zc
  for (int i = 0; i < 16; ++i) {
    int c = c0 * 16 + i;
    XG[c * 64 + ml] = Zc[base_k + (size_t)c * HWp + ml];
  }
  __syncthreads();

  // phase 6: av += Zc @ Wv2c[0:64]; write VH
  {
    const float* Wv = ws + OFF_WV2;
#pragma unroll 4
    for (int kk = 0; kk < 64; ++kk) {
      const float4 a = *(const float4*)&XG[kk * 64 + rg * 4];
      const float4 w = *(const float4*)&Wv[kk * 64 + cg * 4];
      FMA16(av, a, w)
    }
    for (int r = 0; r < 4; ++r)
      *(float4*)&VH[(rg * 4 + r) * 64 + cg * 4] = make_float4(av[r][0], av[r][1], av[r][2], av[r][3]);
  }
  __syncthreads();

  // phase 7: attention
  if (t < 32) {
    int pl = t >> 2, h = t & 3;
    float q[16];
    for (int d = 0; d < 16; ++d) q[d] = QH[pl * 64 + h * 16 + d];
    float s[8], mx = -1e30f;
    for (int k = 0; k < 8; ++k) {
      float sc = 0.f;
      for (int d = 0; d < 16; ++d) sc += q[d] * KH[(pl * 8 + k) * 64 + h * 16 + d];
      s[k] = sc * 0.25f;
      mx = fmaxf(mx, s[k]);
    }
    float sum = 0.f;
    for (int k = 0; k < 8; ++k) { s[k] = expf(s[k] - mx); sum += s[k]; }
    float inv = 1.f / sum;
    for (int d = 0; d < 16; ++d) {
      float o = 0.f;
      for (int k = 0; k < 8; ++k) o += s[k] * VH[(pl * 8 + k) * 64 + h * 16 + d];
      AO[pl * 64 + h * 16 + d] = o * inv;
    }
  }
  __syncthreads();

  // phase 8: out projection -> d_out [B,E,H,W]
  if (t < 128) {
    int row = t >> 4, cq = t & 15;
    const float* Wo = ws + OFF_WO;
    float a0[4];
    for (int c = 0; c < 4; ++c) a0[c] = outb[cq * 4 + c];
#pragma unroll 4
    for (int kk = 0; kk < 64; ++kk) {
      float a = AO[row * 64 + kk];
      const float4 w = *(const float4*)&Wo[kk * 64 + cq * 4];
      a0[0] += a * w.x; a0[1] += a * w.y; a0[2] += a * w.z; a0[3] += a * w.w;
    }
    for (int c = 0; c < 4; ++c)
      out[((size_t)(b * 64 + cq * 4 + c)) * HWp + p0 + row] = a0[c];
  }
}

extern "C" void kernel_launch(void* const* d_in, const int* in_sizes, int n_in,
                              void* d_out, int out_size, void* d_ws, size_t ws_size,
                              hipStream_t stream) {
  const float* HFs = (const float*)d_in[0];
  const float* HFc = (const float*)d_in[1];
  const float* Zc  = (const float*)d_in[2];
  const float* q1w = (const float*)d_in[3];  const float* q1b = (const float*)d_in[4];
  const float* k1w = (const float*)d_in[5];  const float* k1b = (const float*)d_in[6];
  const float* v1w = (const float*)d_in[7];  const float* v1b = (const float*)d_in[8];
  const float* q2w = (const float*)d_in[9];  const float* q2b = (const float*)d_in[10];
  const float* k2w = (const float*)d_in[11]; const float* k2b = (const float*)d_in[12];
  const float* v2w = (const float*)d_in[13]; const float* v2b = (const float*)d_in[14];
  const float* ipw = (const float*)d_in[15]; const float* ipb = (const float*)d_in[16];
  const float* ow  = (const float*)d_in[17]; const float* ob  = (const float*)d_in[18];
  float* ws = (float*)d_ws;
  float* out = (float*)d_out;

  dim3 gsetup(33, 7);
  setup_weights<<<gsetup, 256, 0, stream>>>(q1w, q1b, k1w, k1b, v1w, v1b,
                                            q2w, q2b, k2w, k2b, v2w, v2b, ipw, ipb, ow, ws);
  stage1<<<8192, 256, 0, stream>>>(HFs, HFc, Zc, ws, ob);
  stage2<<<8192, 256, 0, stream>>>(HFs, HFc, Zc, ws, ob, out);
}

// Round 2
// 541.725 us; speedup vs baseline: 1.8480x; 1.8480x over previous
//
#include <hip/hip_runtime.h>
#include <math.h>

#define HWp 16384
#define CH 64
#define KC 8
#define WSTRIDE 136

typedef __attribute__((ext_vector_type(8))) short bf16x8;
typedef __attribute__((ext_vector_type(4))) float f32x4;

#define MFMA(a, b, c) __builtin_amdgcn_mfma_f32_16x16x32_bf16(a, b, c, 0, 0, 0)

__device__ __forceinline__ short f2bf(float f) {
  unsigned u = __float_as_uint(f);
  u += 0x7FFFu + ((u >> 16) & 1u);   // round-to-nearest-even
  return (short)(u >> 16);
}
__device__ __forceinline__ float bf2f(short s) {
  return __uint_as_float(((unsigned)(unsigned short)s) << 16);
}

// B-fragment: B[k=c][n=e] = W[e][c], lane l reads 8 contiguous c at e = nrow
__device__ __forceinline__ bf16x8 ldB(const short* __restrict__ W, int nrow, int c0) {
  return *(const bf16x8*)(W + nrow * WSTRIDE + c0);
}
// A-fragment gather from channel-major global tensor: A[m=row][k=c]
__device__ __forceinline__ bf16x8 ldA_g(const float* __restrict__ base, int c0, int row) {
  bf16x8 f;
#pragma unroll
  for (int j = 0; j < 8; ++j) f[j] = f2bf(base[(size_t)(c0 + j) * HWp + row]);
  return f;
}
// A-fragment from bf16 row-major z: 16B contiguous
__device__ __forceinline__ bf16x8 ldA_z(const short* __restrict__ zrow, int c0) {
  return *(const bf16x8*)(zrow + c0);
}

// Fold MHA in-projection into q/k/v linears; store W^T[e][c] bf16 (stride 136) + biases fp32.
__global__ void setup_weights(const float* __restrict__ q1w, const float* __restrict__ q1b,
                              const float* __restrict__ k1w, const float* __restrict__ k1b,
                              const float* __restrict__ v1w, const float* __restrict__ v1b,
                              const float* __restrict__ q2w, const float* __restrict__ q2b,
                              const float* __restrict__ k2w, const float* __restrict__ k2b,
                              const float* __restrict__ v2w, const float* __restrict__ v2b,
                              const float* __restrict__ ipw, const float* __restrict__ ipb,
                              const float* __restrict__ ow, short* __restrict__ Wt,
                              float* __restrict__ Bc) {
  int id = blockIdx.y;
  int idx = blockIdx.x * 256 + threadIdx.x;
  if (id == 6) {  // out_w: B[k=d][n=e] = ow[e][d] -> store row-major [e][d] bf16
    if (idx < 4096) {
      int e = idx >> 6, d = idx & 63;
      Wt[(6 * 64 + e) * WSTRIDE + d] = f2bf(ow[e * 64 + d]);
    }
    return;
  }
  const float* lw; const float* lb; int K, off;
  switch (id) {
    case 0:  lw = q1w; lb = q1b; K = 66;  off = 0;   break;
    case 1:  lw = k1w; lb = k1b; K = 66;  off = 64;  break;
    case 2:  lw = v1w; lb = v1b; K = 64;  off = 128; break;
    case 3:  lw = q2w; lb = q2b; K = 130; off = 0;   break;
    case 4:  lw = k2w; lb = k2b; K = 130; off = 64;  break;
    default: lw = v2w; lb = v2b; K = 128; off = 128; break;
  }
  if (idx < K * 64) {
    int c = idx >> 6, e = idx & 63;
    float s = 0.f;
    for (int f = 0; f < 64; ++f) s += ipw[(off + e) * 64 + f] * lw[f * K + c];
    Wt[(id * 64 + e) * WSTRIDE + c] = f2bf(s);
  } else if (idx < K * 64 + 64) {
    int e = idx - K * 64;
    float s = ipb[off + e];
    for (int f = 0; f < 64; ++f) s += ipw[(off + e) * 64 + f] * lb[f];
    Bc[id * 64 + e] = s;
  }
}

// ---------------- Stage 1 ----------------
__global__ __launch_bounds__(256) void stage1(const float* __restrict__ HFs,
                                              const float* __restrict__ HFc,
                                              const float* __restrict__ Zc,
                                              const short* __restrict__ Wt,
                                              const float* __restrict__ Bc,
                                              const float* __restrict__ outb,
                                              short* __restrict__ zb) {
  const int t = threadIdx.x;
  const int wv = t >> 6, l = t & 63;
  const int tile = blockIdx.x;
  const int b = tile >> 11;
  const int p0 = (tile & 2047) << 3;
  const int m0 = p0 << 3;
  const int k0 = m0 >> 14;
  const int poff = m0 & (HWp - 1);

  __shared__ float KV[64 * 77];
  __shared__ float QH[8 * 68];
  __shared__ float AO[8 * 68];
  __shared__ float ATT[256];

  const int am = l & 15, kg = l >> 4, n = l & 15;
  const int row0 = wv * 16;

  const short* Wq = Wt + 0 * 64 * WSTRIDE;
  const short* Wk = Wt + 1 * 64 * WSTRIDE;
  const short* Wv = Wt + 2 * 64 * WSTRIDE;
  const short* Wo = Wt + 6 * 64 * WSTRIDE;
  const float* BQ = Bc + 0 * 64;
  const float* BK = Bc + 1 * 64;
  const float* BV = Bc + 2 * 64;

  const float* baseKc = HFc + ((size_t)(b * KC + k0) * CH) * HWp + poff;
  const float* baseZc = Zc + ((size_t)(b * KC + k0) * CH) * HWp + poff;
  const float* baseQ = HFs + (size_t)b * CH * HWp;
  const float inv127 = 1.f / 127.f;

  // ---- K-GEMM (64x64x64 + coords) & Q-GEMM (col-tile per wave) ----
  f32x4 kacc[4];
#pragma unroll
  for (int ct = 0; ct < 4; ++ct) {
    int col = ct * 16 + n;
    float bk = BK[col];
    float wi = bf2f(Wk[col * WSTRIDE + 64]);
    float wj = bf2f(Wk[col * WSTRIDE + 65]);
#pragma unroll
    for (int r = 0; r < 4; ++r) {
      int pp = poff + row0 + kg * 4 + r;
      kacc[ct][r] = bk + (float)(pp >> 7) * inv127 * wi + (float)(pp & 127) * inv127 * wj;
    }
  }
  f32x4 qacc;
  {
    int colq = wv * 16 + n;
    float bq = BQ[colq];
    float wi = bf2f(Wq[colq * WSTRIDE + 64]);
    float wj = bf2f(Wq[colq * WSTRIDE + 65]);
#pragma unroll
    for (int r = 0; r < 4; ++r) {
      int p = p0 + ((kg * 4 + r) & 7);
      qacc[r] = bq + (float)(p >> 7) * inv127 * wi + (float)(p & 127) * inv127 * wj;
    }
  }
#pragma unroll
  for (int ks = 0; ks < 2; ++ks) {
    int c0 = ks * 32 + kg * 8;
    bf16x8 a = ldA_g(baseKc, c0, row0 + am);
#pragma unroll
    for (int ct = 0; ct < 4; ++ct) kacc[ct] = MFMA(a, ldB(Wk, ct * 16 + n, c0), kacc[ct]);
    bf16x8 aq = ldA_g(baseQ, c0, p0 + (am & 7));
    qacc = MFMA(aq, ldB(Wq, wv * 16 + n, c0), qacc);
  }
#pragma unroll
  for (int ct = 0; ct < 4; ++ct)
#pragma unroll
    for (int r = 0; r < 4; ++r)
      KV[(row0 + kg * 4 + r) * 77 + ct * 16 + n] = kacc[ct][r];
#pragma unroll
  for (int r = 0; r < 4; ++r) {
    int m = kg * 4 + r;
    if (m < 8) QH[m * 68 + wv * 16 + n] = qacc[r];
  }
  __syncthreads();

  // ---- scores: thread = (pixel, head, key), softmax over 8 lanes ----
  {
    int p = t >> 5, k = t & 7, h = (t >> 3) & 3;
    const float* qrow = &QH[p * 68 + h * 16];
    const float* krow = &KV[(p * 8 + k) * 77 + h * 16];
    float s = 0.f;
#pragma unroll
    for (int d = 0; d < 16; ++d) s += qrow[d] * krow[d];
    s *= 0.25f;
    float mx = s;
    mx = fmaxf(mx, __shfl_xor(mx, 1));
    mx = fmaxf(mx, __shfl_xor(mx, 2));
    mx = fmaxf(mx, __shfl_xor(mx, 4));
    float e = __expf(s - mx);
    float sum = e;
    sum += __shfl_xor(sum, 1);
    sum += __shfl_xor(sum, 2);
    sum += __shfl_xor(sum, 4);
    ATT[t] = e / sum;
  }
  __syncthreads();

  // ---- V-GEMM (overwrites KV buffer) ----
  f32x4 vacc[4];
#pragma unroll
  for (int ct = 0; ct < 4; ++ct) {
    float bv = BV[ct * 16 + n];
#pragma unroll
    for (int r = 0; r < 4; ++r) vacc[ct][r] = bv;
  }
#pragma unroll
  for (int ks = 0; ks < 2; ++ks) {
    int c0 = ks * 32 + kg * 8;
    bf16x8 a = ldA_g(baseZc, c0, row0 + am);
#pragma unroll
    for (int ct = 0; ct < 4; ++ct) vacc[ct] = MFMA(a, ldB(Wv, ct * 16 + n, c0), vacc[ct]);
  }
#pragma unroll
  for (int ct = 0; ct < 4; ++ct)
#pragma unroll
    for (int r = 0; r < 4; ++r)
      KV[(row0 + kg * 4 + r) * 77 + ct * 16 + n] = vacc[ct][r];
  __syncthreads();

  // ---- attn @ V: thread = (pixel, head, d-pair) ----
  {
    int p = t >> 5, dp = t & 7, h = (t >> 3) & 3;
    int d0 = h * 16 + dp * 2;
    float o0 = 0.f, o1 = 0.f;
#pragma unroll
    for (int k = 0; k < 8; ++k) {
      float a = ATT[(t & ~7) + k];
      const float* vrow = &KV[(p * 8 + k) * 77 + d0];
      o0 += a * vrow[0];
      o1 += a * vrow[1];
    }
    AO[p * 68 + d0] = o0;
    AO[p * 68 + d0 + 1] = o1;
  }
  __syncthreads();

  // ---- out-proj -> z (bf16 in ws) ----
  {
    int colo = wv * 16 + n;
    f32x4 oacc;
    float bo = outb[colo];
#pragma unroll
    for (int r = 0; r < 4; ++r) oacc[r] = bo;
#pragma unroll
    for (int ks = 0; ks < 2; ++ks) {
      int c0 = ks * 32 + kg * 8;
      bf16x8 a;
#pragma unroll
      for (int j = 0; j < 8; ++j) a[j] = f2bf(AO[(am & 7) * 68 + c0 + j]);
      oacc = MFMA(a, ldB(Wo, colo, c0), oacc);
    }
#pragma unroll
    for (int r = 0; r < 4; ++r) {
      int m = kg * 4 + r;
      if (m < 8) zb[((size_t)(b * HWp + p0 + m)) * 64 + colo] = f2bf(oacc[r]);
    }
  }
}

// ---------------- Stage 2 ----------------
__global__ __launch_bounds__(256) void stage2(const float* __restrict__ HFs,
                                              const float* __restrict__ HFc,
                                              const float* __restrict__ Zc,
                                              const short* __restrict__ Wt,
                                              const float* __restrict__ Bc,
                                              const float* __restrict__ outb,
                                              const short* __restrict__ zb,
                                              float* __restrict__ out) {
  const int t = threadIdx.x;
  const int wv = t >> 6, l = t & 63;
  const int tile = blockIdx.x;
  const int b = tile >> 11;
  const int p0 = (tile & 2047) << 3;
  const int m0 = p0 << 3;
  const int k0 = m0 >> 14;
  const int poff = m0 & (HWp - 1);

  __shared__ float KV[64 * 77];
  __shared__ float QH[8 * 68];
  __shared__ float AO[8 * 68];
  __shared__ float ATT[256];

  const int am = l & 15, kg = l >> 4, n = l & 15;
  const int row0 = wv * 16;

  const short* Wq = Wt + 3 * 64 * WSTRIDE;
  const short* Wk = Wt + 4 * 64 * WSTRIDE;
  const short* Wv = Wt + 5 * 64 * WSTRIDE;
  const short* Wo = Wt + 6 * 64 * WSTRIDE;
  const float* BQ = Bc + 3 * 64;
  const float* BK = Bc + 4 * 64;
  const float* BV = Bc + 5 * 64;

  const float* baseKc = HFc + ((size_t)(b * KC + k0) * CH) * HWp + poff;
  const float* baseZc = Zc + ((size_t)(b * KC + k0) * CH) * HWp + poff;
  const float* baseQ = HFs + (size_t)b * CH * HWp;
  const short* zK = zb + ((size_t)(b * HWp + poff + row0 + am)) * 64;  // key-row z
  const short* zQ = zb + ((size_t)(b * HWp + p0 + (am & 7))) * 64;     // query z
  const float inv127 = 1.f / 127.f;

  // ---- K-GEMM: [Kc | z | coords] @ Wk2c ----
  f32x4 kacc[4];
#pragma unroll
  for (int ct = 0; ct < 4; ++ct) {
    int col = ct * 16 + n;
    float bk = BK[col];
    float wi = bf2f(Wk[col * WSTRIDE + 128]);
    float wj = bf2f(Wk[col * WSTRIDE + 129]);
#pragma unroll
    for (int r = 0; r < 4; ++r) {
      int pp = poff + row0 + kg * 4 + r;
      kacc[ct][r] = bk + (float)(pp >> 7) * inv127 * wi + (float)(pp & 127) * inv127 * wj;
    }
  }
  f32x4 qacc;
  {
    int colq = wv * 16 + n;
    float bq = BQ[colq];
    float wi = bf2f(Wq[colq * WSTRIDE + 128]);
    float wj = bf2f(Wq[colq * WSTRIDE + 129]);
#pragma unroll
    for (int r = 0; r < 4; ++r) {
      int p = p0 + ((kg * 4 + r) & 7);
      qacc[r] = bq + (float)(p >> 7) * inv127 * wi + (float)(p & 127) * inv127 * wj;
    }
  }
#pragma unroll
  for (int ks = 0; ks < 4; ++ks) {
    int c0 = ks * 32 + kg * 8;
    bf16x8 a = (ks < 2) ? ldA_g(baseKc, c0, row0 + am) : ldA_z(zK, c0 - 64);
#pragma unroll
    for (int ct = 0; ct < 4; ++ct) kacc[ct] = MFMA(a, ldB(Wk, ct * 16 + n, c0), kacc[ct]);
    bf16x8 aq = (ks < 2) ? ldA_g(baseQ, c0, p0 + (am & 7)) : ldA_z(zQ, c0 - 64);
    qacc = MFMA(aq, ldB(Wq, wv * 16 + n, c0), qacc);
  }
#pragma unroll
  for (int ct = 0; ct < 4; ++ct)
#pragma unroll
    for (int r = 0; r < 4; ++r)
      KV[(row0 + kg * 4 + r) * 77 + ct * 16 + n] = kacc[ct][r];
#pragma unroll
  for (int r = 0; r < 4; ++r) {
    int m = kg * 4 + r;
    if (m < 8) QH[m * 68 + wv * 16 + n] = qacc[r];
  }
  __syncthreads();

  // ---- scores ----
  {
    int p = t >> 5, k = t & 7, h = (t >> 3) & 3;
    const float* qrow = &QH[p * 68 + h * 16];
    const float* krow = &KV[(p * 8 + k) * 77 + h * 16];
    float s = 0.f;
#pragma unroll
    for (int d = 0; d < 16; ++d) s += qrow[d] * krow[d];
    s *= 0.25f;
    float mx = s;
    mx = fmaxf(mx, __shfl_xor(mx, 1));
    mx = fmaxf(mx, __shfl_xor(mx, 2));
    mx = fmaxf(mx, __shfl_xor(mx, 4));
    float e = __expf(s - mx);
    float sum = e;
    sum += __shfl_xor(sum, 1);
    sum += __shfl_xor(sum, 2);
    sum += __shfl_xor(sum, 4);
    ATT[t] = e / sum;
  }
  __syncthreads();

  // ---- V-GEMM: [Zc | z] @ Wv2c ----
  f32x4 vacc[4];
#pragma unroll
  for (int ct = 0; ct < 4; ++ct) {
    float bv = BV[ct * 16 + n];
#pragma unroll
    for (int r = 0; r < 4; ++r) vacc[ct][r] = bv;
  }
#pragma unroll
  for (int ks = 0; ks < 4; ++ks) {
    int c0 = ks * 32 + kg * 8;
    bf16x8 a = (ks < 2) ? ldA_g(baseZc, c0, row0 + am) : ldA_z(zK, c0 - 64);
#pragma unroll
    for (int ct = 0; ct < 4; ++ct) vacc[ct] = MFMA(a, ldB(Wv, ct * 16 + n, c0), vacc[ct]);
  }
#pragma unroll
  for (int ct = 0; ct < 4; ++ct)
#pragma unroll
    for (int r = 0; r < 4; ++r)
      KV[(row0 + kg * 4 + r) * 77 + ct * 16 + n] = vacc[ct][r];
  __syncthreads();

  // ---- attn @ V ----
  {
    int p = t >> 5, dp = t & 7, h = (t >> 3) & 3;
    int d0 = h * 16 + dp * 2;
    float o0 = 0.f, o1 = 0.f;
#pragma unroll
    for (int k = 0; k < 8; ++k) {
      float a = ATT[(t & ~7) + k];
      const float* vrow = &KV[(p * 8 + k) * 77 + d0];
      o0 += a * vrow[0];
      o1 += a * vrow[1];
    }
    AO[p * 68 + d0] = o0;
    AO[p * 68 + d0 + 1] = o1;
  }
  __syncthreads();

  // ---- out-proj -> d_out [B,E,H,W] fp32 ----
  {
    int colo = wv * 16 + n;
    f32x4 oacc;
    float bo = outb[colo];
#pragma unroll
    for (int r = 0; r < 4; ++r) oacc[r] = bo;
#pragma unroll
    for (int ks = 0; ks < 2; ++ks) {
      int c0 = ks * 32 + kg * 8;
      bf16x8 a;
#pragma unroll
      for (int j = 0; j < 8; ++j) a[j] = f2bf(AO[(am & 7) * 68 + c0 + j]);
      oacc = MFMA(a, ldB(Wo, colo, c0), oacc);
    }
#pragma unroll
    for (int r = 0; r < 4; ++r) {
      int m = kg * 4 + r;
      if (m < 8) out[((size_t)(b * 64 + colo)) * HWp + p0 + m] = oacc[r];
    }
  }
}

extern "C" void kernel_launch(void* const* d_in, const int* in_sizes, int n_in,
                              void* d_out, int out_size, void* d_ws, size_t ws_size,
                              hipStream_t stream) {
  const float* HFs = (const float*)d_in[0];
  const float* HFc = (const float*)d_in[1];
  const float* Zc = (const float*)d_in[2];
  const float* q1w = (const float*)d_in[3];  const float* q1b = (const float*)d_in[4];
  const float* k1w = (const float*)d_in[5];  const float* k1b = (const float*)d_in[6];
  const float* v1w = (const float*)d_in[7];  const float* v1b = (const float*)d_in[8];
  const float* q2w = (const float*)d_in[9];  const float* q2b = (const float*)d_in[10];
  const float* k2w = (const float*)d_in[11]; const float* k2b = (const float*)d_in[12];
  const float* v2w = (const float*)d_in[13]; const float* v2b = (const float*)d_in[14];
  const float* ipw = (const float*)d_in[15]; const float* ipb = (const float*)d_in[16];
  const float* ow = (const float*)d_in[17];  const float* ob = (const float*)d_in[18];

  short* Wt = (short*)d_ws;                          // 7 x 64 x 136 bf16 = 121856 B
  float* Bc = (float*)((char*)d_ws + 121856);        // 6 x 64 fp32
  short* zb = (short*)((char*)d_ws + 131072);        // B*HW*64 bf16 = 8.39 MB
  float* out = (float*)d_out;

  dim3 gsetup(33, 7);
  setup_weights<<<gsetup, 256, 0, stream>>>(q1w, q1b, k1w, k1b, v1w, v1b,
                                            q2w, q2b, k2w, k2b, v2w, v2b,
                                            ipw, ipb, ow, Wt, Bc);
  stage1<<<8192, 256, 0, stream>>>(HFs, HFc, Zc, Wt, Bc, ob, zb);
  stage2<<<8192, 256, 0, stream>>>(HFs, HFc, Zc, Wt, Bc, ob, zb, out);
}